// Round 1
// baseline (439.392 us; speedup 1.0000x reference)
//
#include <hip/hip_runtime.h>

#define N_NODES 50000
#define DIM 128
#define HID 32

// ---------------- deg count: in-degree over targets (col) ----------------
__global__ __launch_bounds__(256) void deg_count_kernel(const int* __restrict__ col,
                                                        int* __restrict__ degi, int E) {
    int e = blockIdx.x * 256 + threadIdx.x;
    if (e < E) atomicAdd(&degi[col[e]], 1);
}

// ---------------- dinv = rsqrt(deg + 1)  (self-loop included) ----------------
__global__ __launch_bounds__(256) void dinv_kernel(const int* __restrict__ degi,
                                                   float* __restrict__ dinv, int n) {
    int i = blockIdx.x * 256 + threadIdx.x;
    if (i < n) dinv[i] = rsqrtf((float)degi[i] + 1.0f);
}

// ---------------- xw = x @ W  ([N,128] @ [128,128]) ----------------
// 8 rows per block, 256 threads: thread computes 4 outputs (4 rows x 1 col).
__global__ __launch_bounds__(256) void gemm_xw_kernel(const float* __restrict__ x,
                                                      const float* __restrict__ W,
                                                      float* __restrict__ xw, int n) {
    __shared__ float xs[8 * 128];
    int t = threadIdx.x;
    int row0 = blockIdx.x * 8;
    long base = (long)row0 * DIM;
#pragma unroll
    for (int i = 0; i < 4; ++i) {
        int idx = t + i * 256;
        int rl = idx >> 7;
        xs[idx] = (row0 + rl < n) ? x[base + idx] : 0.0f;
    }
    __syncthreads();
    int col = t & 127;
    int rbase = (t >> 7) * 4;  // 0 or 4
    float a0 = 0.f, a1 = 0.f, a2 = 0.f, a3 = 0.f;
    for (int k = 0; k < DIM; ++k) {
        float wv = W[k * DIM + col];
        a0 += xs[(rbase + 0) * DIM + k] * wv;
        a1 += xs[(rbase + 1) * DIM + k] * wv;
        a2 += xs[(rbase + 2) * DIM + k] * wv;
        a3 += xs[(rbase + 3) * DIM + k] * wv;
    }
    if (row0 + rbase + 3 < n) {
        xw[base + (rbase + 0) * DIM + col] = a0;
        xw[base + (rbase + 1) * DIM + col] = a1;
        xw[base + (rbase + 2) * DIM + col] = a2;
        xw[base + (rbase + 3) * DIM + col] = a3;
    } else {
        if (row0 + rbase + 0 < n) xw[base + (rbase + 0) * DIM + col] = a0;
        if (row0 + rbase + 1 < n) xw[base + (rbase + 1) * DIM + col] = a1;
        if (row0 + rbase + 2 < n) xw[base + (rbase + 2) * DIM + col] = a2;
    }
}

// ---------------- edge scatter: scat[col] += xw[row] * dinv[row]*dinv[col] ----------------
// One wave (64 lanes) per edge; each lane handles 2 of the 128 channels.
__global__ __launch_bounds__(256) void edge_scatter_kernel(const int* __restrict__ ei,
                                                           const float* __restrict__ xw,
                                                           const float* __restrict__ dinv,
                                                           float* __restrict__ scat, int E) {
    int e = blockIdx.x * 4 + (threadIdx.x >> 6);
    int lane = threadIdx.x & 63;
    if (e >= E) return;
    int row = ei[e];        // source
    int col = ei[E + e];    // target
    float norm = dinv[row] * dinv[col];
    const float* src = xw + (long)row * DIM;
    float* dst = scat + (long)col * DIM;
    unsafeAtomicAdd(&dst[lane], src[lane] * norm);
    unsafeAtomicAdd(&dst[lane + 64], src[lane + 64] * norm);
}

// ---------------- fused tail: self-loop + bias + relu + residual + MLP ----------------
// 8 rows per block; 32 threads per row for the MLP stages.
__global__ __launch_bounds__(256) void fused_tail_kernel(
    const float* __restrict__ scat, const float* __restrict__ xw,
    const float* __restrict__ x, const float* __restrict__ dinv,
    const float* __restrict__ b_gcn,
    const float* __restrict__ w1, const float* __restrict__ b1,
    const float* __restrict__ w2, const float* __restrict__ b2,
    const float* __restrict__ w3, const float* __restrict__ b3,
    float* __restrict__ out, int n) {
    __shared__ float hs[8 * 132];   // stride 132 breaks 8-way bank conflicts
    __shared__ float t1s[8 * 33];
    __shared__ float t2s[8 * 33];
    int t = threadIdx.x;
    int row0 = blockIdx.x * 8;
    long base = (long)row0 * DIM;
#pragma unroll
    for (int i = 0; i < 4; ++i) {
        int idx = t + i * 256;
        int rl = idx >> 7, k = idx & 127;
        int row = row0 + rl;
        float v = 0.0f;
        if (row < n) {
            float dv = dinv[row];
            float g = scat[base + idx] + xw[base + idx] * dv * dv + b_gcn[k];
            g = fmaxf(g, 0.0f);
            v = g + x[base + idx];
        }
        hs[rl * 132 + k] = v;
    }
    __syncthreads();
    int r = t >> 5, j = t & 31;
    float acc = b1[j];
    for (int k = 0; k < DIM; ++k) acc += hs[r * 132 + k] * w1[k * HID + j];
    t1s[r * 33 + j] = fmaxf(acc, 0.0f);
    __syncthreads();
    acc = b2[j];
    for (int k = 0; k < HID; ++k) acc += t1s[r * 33 + k] * w2[k * HID + j];
    t2s[r * 33 + j] = fmaxf(acc, 0.0f);
    __syncthreads();
    if (j == 0 && row0 + r < n) {
        float s = b3[0];
        for (int k = 0; k < HID; ++k) s += t2s[r * 33 + k] * w3[k];
        out[row0 + r] = s;
    }
}

extern "C" void kernel_launch(void* const* d_in, const int* in_sizes, int n_in,
                              void* d_out, int out_size, void* d_ws, size_t ws_size,
                              hipStream_t stream) {
    const float* x     = (const float*)d_in[0];
    const int*   ei    = (const int*)d_in[1];
    const float* W_gcn = (const float*)d_in[2];
    const float* b_gcn = (const float*)d_in[3];
    const float* w1    = (const float*)d_in[4];
    const float* b1    = (const float*)d_in[5];
    const float* w2    = (const float*)d_in[6];
    const float* b2    = (const float*)d_in[7];
    const float* w3    = (const float*)d_in[8];
    const float* b3    = (const float*)d_in[9];
    float* out = (float*)d_out;

    const int n = in_sizes[0] / DIM;     // 50000
    const int E = in_sizes[1] / 2;       // 600000

    // workspace layout
    char* ws = (char*)d_ws;
    size_t xw_bytes   = (size_t)n * DIM * sizeof(float);   // 25.6 MB
    float* xw   = (float*)(ws);
    float* scat = (float*)(ws + xw_bytes);
    int*   degi = (int*)  (ws + 2 * xw_bytes);
    float* dinv = (float*)(ws + 2 * xw_bytes + (size_t)n * sizeof(int));

    // zero scat + degi in one shot (contiguous)
    hipMemsetAsync(ws + xw_bytes, 0, xw_bytes + (size_t)n * sizeof(int), stream);

    deg_count_kernel<<<(E + 255) / 256, 256, 0, stream>>>(ei + E, degi, E);
    dinv_kernel<<<(n + 255) / 256, 256, 0, stream>>>(degi, dinv, n);
    gemm_xw_kernel<<<(n + 7) / 8, 256, 0, stream>>>(x, W_gcn, xw, n);
    edge_scatter_kernel<<<(E + 3) / 4, 256, 0, stream>>>(ei, xw, dinv, scat, E);
    fused_tail_kernel<<<(n + 7) / 8, 256, 0, stream>>>(scat, xw, x, dinv, b_gcn,
                                                       w1, b1, w2, b2, w3, b3, out, n);
}

// Round 2
// 273.056 us; speedup vs baseline: 1.6092x; 1.6092x over previous
//
#include <hip/hip_runtime.h>

#define DIM 128
#define HID 32

// ---------------- deg count: in-degree over targets (col) ----------------
__global__ __launch_bounds__(256) void deg_count_kernel(const int* __restrict__ col,
                                                        int* __restrict__ degi, int E) {
    int e = blockIdx.x * 256 + threadIdx.x;
    if (e < E) atomicAdd(&degi[col[e]], 1);
}

// ---------------- dinv = rsqrt(deg + 1)  (self-loop included) ----------------
__global__ __launch_bounds__(256) void dinv_kernel(const int* __restrict__ degi,
                                                   float* __restrict__ dinv, int n) {
    int i = blockIdx.x * 256 + threadIdx.x;
    if (i < n) dinv[i] = rsqrtf((float)degi[i] + 1.0f);
}

// ---------------- scan stage A: per-block exclusive scan + block sums ----------------
__global__ __launch_bounds__(1024) void scan_blocks_kernel(const int* __restrict__ degi,
                                                           int* __restrict__ offs,
                                                           int* __restrict__ bsum, int n) {
    __shared__ int s[1024];
    int i = blockIdx.x * 1024 + threadIdx.x;
    int v = (i < n) ? degi[i] : 0;
    s[threadIdx.x] = v;
    __syncthreads();
    for (int off = 1; off < 1024; off <<= 1) {
        int t = (threadIdx.x >= off) ? s[threadIdx.x - off] : 0;
        __syncthreads();
        s[threadIdx.x] += t;
        __syncthreads();
    }
    if (i < n) offs[i] = s[threadIdx.x] - v;   // exclusive within block
    if (threadIdx.x == 1023) bsum[blockIdx.x] = s[1023];
}

// ---------------- scan stage B: wave-scan the block sums (nb <= 64) ----------------
__global__ __launch_bounds__(64) void scan_sums_kernel(int* __restrict__ bsum, int nb) {
    int lane = threadIdx.x;
    int v = (lane < nb) ? bsum[lane] : 0;
    int orig = v;
    for (int off = 1; off < 64; off <<= 1) {
        int t = __shfl_up(v, off);
        if (lane >= off) v += t;
    }
    if (lane < nb) bsum[lane] = v - orig;      // exclusive
}

// ---------------- scan stage C: add block prefix; init cursors ----------------
__global__ __launch_bounds__(1024) void scan_add_kernel(int* __restrict__ offs,
                                                        const int* __restrict__ bsum,
                                                        int* __restrict__ cur, int n) {
    int i = blockIdx.x * 1024 + threadIdx.x;
    if (i < n) {
        int o = offs[i] + bsum[blockIdx.x];
        offs[i] = o;
        cur[i] = o;
    }
}

// ---------------- fill CSR buckets: (src, dinv[src]) grouped by target ----------------
__global__ __launch_bounds__(256) void fill_kernel(const int* __restrict__ ei,
                                                   const float* __restrict__ dinv,
                                                   int* __restrict__ cur,
                                                   int* __restrict__ srcs,
                                                   float* __restrict__ dsrc, int E) {
    int e = blockIdx.x * 256 + threadIdx.x;
    if (e >= E) return;
    int r = ei[e];          // source
    int c = ei[E + e];      // target
    int p = atomicAdd(&cur[c], 1);
    srcs[p] = r;
    dsrc[p] = dinv[r];
}

// ---------------- xw = x @ W  ([N,128] @ [128,128]) ----------------
__global__ __launch_bounds__(256) void gemm_xw_kernel(const float* __restrict__ x,
                                                      const float* __restrict__ W,
                                                      float* __restrict__ xw, int n) {
    __shared__ float xs[8 * 128];
    int t = threadIdx.x;
    int row0 = blockIdx.x * 8;
    long base = (long)row0 * DIM;
#pragma unroll
    for (int i = 0; i < 4; ++i) {
        int idx = t + i * 256;
        int rl = idx >> 7;
        xs[idx] = (row0 + rl < n) ? x[base + idx] : 0.0f;
    }
    __syncthreads();
    int col = t & 127;
    int rbase = (t >> 7) * 4;  // 0 or 4
    float a0 = 0.f, a1 = 0.f, a2 = 0.f, a3 = 0.f;
    for (int k = 0; k < DIM; ++k) {
        float wv = W[k * DIM + col];
        a0 += xs[(rbase + 0) * DIM + k] * wv;
        a1 += xs[(rbase + 1) * DIM + k] * wv;
        a2 += xs[(rbase + 2) * DIM + k] * wv;
        a3 += xs[(rbase + 3) * DIM + k] * wv;
    }
    if (row0 + rbase + 3 < n) {
        xw[base + (rbase + 0) * DIM + col] = a0;
        xw[base + (rbase + 1) * DIM + col] = a1;
        xw[base + (rbase + 2) * DIM + col] = a2;
        xw[base + (rbase + 3) * DIM + col] = a3;
    } else {
        if (row0 + rbase + 0 < n) xw[base + (rbase + 0) * DIM + col] = a0;
        if (row0 + rbase + 1 < n) xw[base + (rbase + 1) * DIM + col] = a1;
        if (row0 + rbase + 2 < n) xw[base + (rbase + 2) * DIM + col] = a2;
    }
}

// ---------------- fused: CSR gather + self-loop + bias/relu/residual + MLP ----------------
// 8 nodes per block; 32 threads per node (thread j owns channels 4j..4j+3).
__global__ __launch_bounds__(256) void gather_tail_kernel(
    const float* __restrict__ xw, const float* __restrict__ x,
    const int* __restrict__ offs, const int* __restrict__ degi,
    const int* __restrict__ srcs, const float* __restrict__ dsrc,
    const float* __restrict__ dinv, const float* __restrict__ b_gcn,
    const float* __restrict__ w1, const float* __restrict__ b1,
    const float* __restrict__ w2, const float* __restrict__ b2,
    const float* __restrict__ w3, const float* __restrict__ b3,
    float* __restrict__ out, int n) {
    __shared__ float hs[8 * 132];   // stride 132 breaks bank conflicts
    __shared__ float t1s[8 * 33];
    __shared__ float t2s[8 * 33];
    int t = threadIdx.x;
    int r = t >> 5, j = t & 31;
    int node = blockIdx.x * 8 + r;

    if (node < n) {
        int beg = offs[node];
        int d = degi[node];
        float ax = 0.f, ay = 0.f, az = 0.f, aw = 0.f;
        for (int q = 0; q < d; ++q) {
            int s = srcs[beg + q];
            float w = dsrc[beg + q];
            const float4 v = ((const float4*)(xw + (long)s * DIM))[j];
            ax += w * v.x; ay += w * v.y; az += w * v.z; aw += w * v.w;
        }
        float di = dinv[node];
        float sdi = di * di;
        const float4 a  = ((const float4*)(xw + (long)node * DIM))[j];
        const float4 xv = ((const float4*)(x  + (long)node * DIM))[j];
        const float4 bg = ((const float4*)b_gcn)[j];
        float* h = &hs[r * 132 + 4 * j];
        h[0] = fmaxf(di * ax + sdi * a.x + bg.x, 0.f) + xv.x;
        h[1] = fmaxf(di * ay + sdi * a.y + bg.y, 0.f) + xv.y;
        h[2] = fmaxf(di * az + sdi * a.z + bg.z, 0.f) + xv.z;
        h[3] = fmaxf(di * aw + sdi * a.w + bg.w, 0.f) + xv.w;
    }
    __syncthreads();
    float acc = b1[j];
    for (int k = 0; k < DIM; ++k) acc += hs[r * 132 + k] * w1[k * HID + j];
    t1s[r * 33 + j] = fmaxf(acc, 0.0f);
    __syncthreads();
    acc = b2[j];
    for (int k = 0; k < HID; ++k) acc += t1s[r * 33 + k] * w2[k * HID + j];
    t2s[r * 33 + j] = fmaxf(acc, 0.0f);
    __syncthreads();
    if (j == 0 && node < n) {
        float s = b3[0];
        for (int k = 0; k < HID; ++k) s += t2s[r * 33 + k] * w3[k];
        out[node] = s;
    }
}

extern "C" void kernel_launch(void* const* d_in, const int* in_sizes, int n_in,
                              void* d_out, int out_size, void* d_ws, size_t ws_size,
                              hipStream_t stream) {
    const float* x     = (const float*)d_in[0];
    const int*   ei    = (const int*)d_in[1];
    const float* W_gcn = (const float*)d_in[2];
    const float* b_gcn = (const float*)d_in[3];
    const float* w1    = (const float*)d_in[4];
    const float* b1    = (const float*)d_in[5];
    const float* w2    = (const float*)d_in[6];
    const float* b2    = (const float*)d_in[7];
    const float* w3    = (const float*)d_in[8];
    const float* b3    = (const float*)d_in[9];
    float* out = (float*)d_out;

    const int n = in_sizes[0] / DIM;     // 50000
    const int E = in_sizes[1] / 2;       // 600000

    // workspace layout
    char* ws = (char*)d_ws;
    size_t xw_bytes = (size_t)n * DIM * sizeof(float);   // 25.6 MB
    float* xw   = (float*)(ws);
    char*  p    = ws + xw_bytes;
    int*   degi = (int*)p;           p += (size_t)n * sizeof(int);
    float* dinv = (float*)p;         p += (size_t)n * sizeof(float);
    int*   offs = (int*)p;           p += (size_t)n * sizeof(int);
    int*   cur  = (int*)p;           p += (size_t)n * sizeof(int);
    int*   bsum = (int*)p;           p += 256 * sizeof(int);
    int*   srcs = (int*)p;           p += (size_t)E * sizeof(int);
    float* dsrc = (float*)p;

    const int nb = (n + 1023) / 1024;   // 49 scan blocks

    hipMemsetAsync(degi, 0, (size_t)n * sizeof(int), stream);

    deg_count_kernel<<<(E + 255) / 256, 256, 0, stream>>>(ei + E, degi, E);
    dinv_kernel<<<(n + 255) / 256, 256, 0, stream>>>(degi, dinv, n);
    scan_blocks_kernel<<<nb, 1024, 0, stream>>>(degi, offs, bsum, n);
    scan_sums_kernel<<<1, 64, 0, stream>>>(bsum, nb);
    scan_add_kernel<<<nb, 1024, 0, stream>>>(offs, bsum, cur, n);
    fill_kernel<<<(E + 255) / 256, 256, 0, stream>>>(ei, dinv, cur, srcs, dsrc, E);
    gemm_xw_kernel<<<(n + 7) / 8, 256, 0, stream>>>(x, W_gcn, xw, n);
    gather_tail_kernel<<<(n + 7) / 8, 256, 0, stream>>>(xw, x, offs, degi, srcs, dsrc,
                                                        dinv, b_gcn, w1, b1, w2, b2,
                                                        w3, b3, out, n);
}

// Round 3
// 257.693 us; speedup vs baseline: 1.7051x; 1.0596x over previous
//
#include <hip/hip_runtime.h>

#define DIM 128
#define HID 32

// bf16 helpers (RNE), values finite
static __device__ __forceinline__ unsigned short f2bf(float f) {
    unsigned int u = __float_as_uint(f);
    u += 0x7fffu + ((u >> 16) & 1u);
    return (unsigned short)(u >> 16);
}
static __device__ __forceinline__ float bf2f(unsigned short s) {
    return __uint_as_float((unsigned int)s << 16);
}

// ---------------- deg count: in-degree over targets (col) ----------------
__global__ __launch_bounds__(256) void deg_count_kernel(const int* __restrict__ col,
                                                        int* __restrict__ degi, int E) {
    int e = blockIdx.x * 256 + threadIdx.x;
    if (e < E) atomicAdd(&degi[col[e]], 1);
}

// ---------------- scan stage A: per-block exclusive scan + block sums ----------------
__global__ __launch_bounds__(1024) void scan_blocks_kernel(const int* __restrict__ degi,
                                                           int* __restrict__ offs,
                                                           int* __restrict__ bsum, int n) {
    __shared__ int s[1024];
    int i = blockIdx.x * 1024 + threadIdx.x;
    int v = (i < n) ? degi[i] : 0;
    s[threadIdx.x] = v;
    __syncthreads();
    for (int off = 1; off < 1024; off <<= 1) {
        int t = (threadIdx.x >= off) ? s[threadIdx.x - off] : 0;
        __syncthreads();
        s[threadIdx.x] += t;
        __syncthreads();
    }
    if (i < n) offs[i] = s[threadIdx.x] - v;   // exclusive within block
    if (threadIdx.x == 1023) bsum[blockIdx.x] = s[1023];
}

// ---------------- scan stage B: wave-scan the block sums (nb <= 64) ----------------
__global__ __launch_bounds__(64) void scan_sums_kernel(int* __restrict__ bsum, int nb) {
    int lane = threadIdx.x;
    int v = (lane < nb) ? bsum[lane] : 0;
    int orig = v;
    for (int off = 1; off < 64; off <<= 1) {
        int t = __shfl_up(v, off);
        if (lane >= off) v += t;
    }
    if (lane < nb) bsum[lane] = v - orig;      // exclusive
}

// ---------------- scan stage C: add block prefix; init cursors; dinv ----------------
__global__ __launch_bounds__(1024) void scan_add_kernel(int* __restrict__ offs,
                                                        const int* __restrict__ bsum,
                                                        int* __restrict__ cur,
                                                        const int* __restrict__ degi,
                                                        float* __restrict__ dinv, int n) {
    int i = blockIdx.x * 1024 + threadIdx.x;
    if (i < n) {
        int o = offs[i] + bsum[blockIdx.x];
        offs[i] = o;
        cur[i] = o;
        dinv[i] = rsqrtf((float)degi[i] + 1.0f);   // self-loop included
    }
}

// ---------------- fill CSR buckets: int2{src, bits(dinv[src])} grouped by target ----------------
__global__ __launch_bounds__(256) void fill_kernel(const int* __restrict__ ei,
                                                   const float* __restrict__ dinv,
                                                   int* __restrict__ cur,
                                                   int2* __restrict__ csr, int E) {
    int e = blockIdx.x * 256 + threadIdx.x;
    if (e >= E) return;
    int r = ei[e];          // source
    int c = ei[E + e];      // target
    int p = atomicAdd(&cur[c], 1);
    csr[p] = make_int2(r, __float_as_int(dinv[r]));
}

// ---------------- xw(bf16) = x @ W  ([N,128] @ [128,128]) ----------------
// 16 rows/block, 256 threads; thread = 2 rows x 4 cols register tile.
__global__ __launch_bounds__(256) void gemm_xw_kernel(const float* __restrict__ x,
                                                      const float* __restrict__ W,
                                                      unsigned short* __restrict__ xwb, int n) {
    __shared__ float xs[16 * 128];
    int t = threadIdx.x;
    int row0 = blockIdx.x * 16;
    const float4* xg = (const float4*)(x + (size_t)row0 * DIM);
#pragma unroll
    for (int i = 0; i < 2; ++i) {
        int f = t + i * 256;
        int rl = f >> 5;                       // float4 index -> local row
        float4 v = make_float4(0.f, 0.f, 0.f, 0.f);
        if (row0 + rl < n) v = xg[f];
        ((float4*)xs)[f] = v;
    }
    __syncthreads();
    int j = t & 31;                            // col group (4 cols)
    int rr = t >> 5;                           // local rows rr and rr+8
    float a0x = 0.f, a0y = 0.f, a0z = 0.f, a0w = 0.f;
    float a1x = 0.f, a1y = 0.f, a1z = 0.f, a1w = 0.f;
    for (int k = 0; k < DIM; k += 4) {
        float4 xa = *(const float4*)&xs[rr * DIM + k];
        float4 xb = *(const float4*)&xs[(rr + 8) * DIM + k];
#pragma unroll
        for (int i = 0; i < 4; ++i) {
            float4 wv = *(const float4*)&W[(k + i) * DIM + 4 * j];
            float xai = (i == 0) ? xa.x : (i == 1) ? xa.y : (i == 2) ? xa.z : xa.w;
            float xbi = (i == 0) ? xb.x : (i == 1) ? xb.y : (i == 2) ? xb.z : xb.w;
            a0x += xai * wv.x; a0y += xai * wv.y; a0z += xai * wv.z; a0w += xai * wv.w;
            a1x += xbi * wv.x; a1y += xbi * wv.y; a1z += xbi * wv.z; a1w += xbi * wv.w;
        }
    }
    int rowA = row0 + rr, rowB = row0 + rr + 8;
    if (rowA < n) {
        ushort4 o; o.x = f2bf(a0x); o.y = f2bf(a0y); o.z = f2bf(a0z); o.w = f2bf(a0w);
        ((ushort4*)(xwb + (size_t)rowA * DIM))[j] = o;
    }
    if (rowB < n) {
        ushort4 o; o.x = f2bf(a1x); o.y = f2bf(a1y); o.z = f2bf(a1z); o.w = f2bf(a1w);
        ((ushort4*)(xwb + (size_t)rowB * DIM))[j] = o;
    }
}

// ---------------- fused: CSR gather + self-loop + bias/relu/residual + MLP ----------------
// 8 nodes/block; 32 threads/node; thread j owns channels 4j..4j+3.
__global__ __launch_bounds__(256) void gather_tail_kernel(
    const unsigned short* __restrict__ xwb, const float* __restrict__ x,
    const int* __restrict__ offs, const int* __restrict__ degi,
    const int2* __restrict__ csr,
    const float* __restrict__ dinv, const float* __restrict__ b_gcn,
    const float* __restrict__ w1, const float* __restrict__ b1,
    const float* __restrict__ w2, const float* __restrict__ b2,
    const float* __restrict__ w3, const float* __restrict__ b3,
    float* __restrict__ out, int n) {
    __shared__ float hs[8 * 132];   // 132*4B = 16B-aligned rows, conflict-free
    __shared__ float t1s[8 * 40];   // 40*4B = 160B, 16B-aligned rows
    int t = threadIdx.x;
    int r = t >> 5, j = t & 31;
    int node = blockIdx.x * 8 + r;

    if (node < n) {
        int beg = offs[node];
        int end = beg + degi[node];
        float ax = 0.f, ay = 0.f, az = 0.f, aw = 0.f;
        int q = beg;
        for (; q + 2 <= end; q += 2) {
            int2 e0 = csr[q];
            int2 e1 = csr[q + 1];
            ushort4 v0 = ((const ushort4*)(xwb + (size_t)e0.x * DIM))[j];
            ushort4 v1 = ((const ushort4*)(xwb + (size_t)e1.x * DIM))[j];
            float w0 = __int_as_float(e0.y);
            float w1_ = __int_as_float(e1.y);
            ax += w0 * bf2f(v0.x) + w1_ * bf2f(v1.x);
            ay += w0 * bf2f(v0.y) + w1_ * bf2f(v1.y);
            az += w0 * bf2f(v0.z) + w1_ * bf2f(v1.z);
            aw += w0 * bf2f(v0.w) + w1_ * bf2f(v1.w);
        }
        if (q < end) {
            int2 e0 = csr[q];
            ushort4 v0 = ((const ushort4*)(xwb + (size_t)e0.x * DIM))[j];
            float w0 = __int_as_float(e0.y);
            ax += w0 * bf2f(v0.x); ay += w0 * bf2f(v0.y);
            az += w0 * bf2f(v0.z); aw += w0 * bf2f(v0.w);
        }
        float di = dinv[node];
        float sdi = di * di;
        ushort4 a = ((const ushort4*)(xwb + (size_t)node * DIM))[j];
        float4 xv = ((const float4*)(x + (size_t)node * DIM))[j];
        float4 bg = ((const float4*)b_gcn)[j];
        float* h = &hs[r * 132 + 4 * j];
        h[0] = fmaxf(di * ax + sdi * bf2f(a.x) + bg.x, 0.f) + xv.x;
        h[1] = fmaxf(di * ay + sdi * bf2f(a.y) + bg.y, 0.f) + xv.y;
        h[2] = fmaxf(di * az + sdi * bf2f(a.z) + bg.z, 0.f) + xv.z;
        h[3] = fmaxf(di * aw + sdi * bf2f(a.w) + bg.w, 0.f) + xv.w;
    }
    __syncthreads();
    // layer 1: 128 -> 32
    float acc = b1[j];
    for (int k = 0; k < DIM; k += 4) {
        float4 hv = *(const float4*)&hs[r * 132 + k];
        acc += hv.x * w1[(k + 0) * HID + j];
        acc += hv.y * w1[(k + 1) * HID + j];
        acc += hv.z * w1[(k + 2) * HID + j];
        acc += hv.w * w1[(k + 3) * HID + j];
    }
    t1s[r * 40 + j] = fmaxf(acc, 0.0f);
    __syncthreads();
    // layer 2: 32 -> 32
    acc = b2[j];
    for (int k = 0; k < HID; k += 4) {
        float4 tv = *(const float4*)&t1s[r * 40 + k];
        acc += tv.x * w2[(k + 0) * HID + j];
        acc += tv.y * w2[(k + 1) * HID + j];
        acc += tv.z * w2[(k + 2) * HID + j];
        acc += tv.w * w2[(k + 3) * HID + j];
    }
    // layer 3: 32 -> 1, shuffle-reduce across the 32 threads of this node
    float v = fmaxf(acc, 0.0f) * w3[j];
#pragma unroll
    for (int off = 16; off > 0; off >>= 1) v += __shfl_down(v, off, 32);
    if (j == 0 && node < n) out[node] = v + b3[0];
}

extern "C" void kernel_launch(void* const* d_in, const int* in_sizes, int n_in,
                              void* d_out, int out_size, void* d_ws, size_t ws_size,
                              hipStream_t stream) {
    const float* x     = (const float*)d_in[0];
    const int*   ei    = (const int*)d_in[1];
    const float* W_gcn = (const float*)d_in[2];
    const float* b_gcn = (const float*)d_in[3];
    const float* w1    = (const float*)d_in[4];
    const float* b1    = (const float*)d_in[5];
    const float* w2    = (const float*)d_in[6];
    const float* b2    = (const float*)d_in[7];
    const float* w3    = (const float*)d_in[8];
    const float* b3    = (const float*)d_in[9];
    float* out = (float*)d_out;

    const int n = in_sizes[0] / DIM;     // 50000
    const int E = in_sizes[1] / 2;       // 600000

    // workspace layout
    char* ws = (char*)d_ws;
    unsigned short* xwb = (unsigned short*)ws;              // 12.8 MB bf16
    char* p = ws + (size_t)n * DIM * sizeof(unsigned short);
    int*   degi = (int*)p;           p += (size_t)n * sizeof(int);
    float* dinv = (float*)p;         p += (size_t)n * sizeof(float);
    int*   offs = (int*)p;           p += (size_t)n * sizeof(int);
    int*   cur  = (int*)p;           p += (size_t)n * sizeof(int);
    int*   bsum = (int*)p;           p += 256 * sizeof(int);
    p = (char*)(((size_t)p + 15) & ~(size_t)15);
    int2*  csr  = (int2*)p;                                  // 4.8 MB

    const int nb = (n + 1023) / 1024;   // 49 scan blocks

    hipMemsetAsync(degi, 0, (size_t)n * sizeof(int), stream);

    deg_count_kernel<<<(E + 255) / 256, 256, 0, stream>>>(ei + E, degi, E);
    scan_blocks_kernel<<<nb, 1024, 0, stream>>>(degi, offs, bsum, n);
    scan_sums_kernel<<<1, 64, 0, stream>>>(bsum, nb);
    scan_add_kernel<<<nb, 1024, 0, stream>>>(offs, bsum, cur, degi, dinv, n);
    fill_kernel<<<(E + 255) / 256, 256, 0, stream>>>(ei, dinv, cur, csr, E);
    gemm_xw_kernel<<<(n + 15) / 16, 256, 0, stream>>>(x, W_gcn, xwb, n);
    gather_tail_kernel<<<(n + 7) / 8, 256, 0, stream>>>(xwb, x, offs, degi, csr,
                                                        dinv, b_gcn, w1, b1, w2, b2,
                                                        w3, b3, out, n);
}